// Round 1
// baseline (835.803 us; speedup 1.0000x reference)
//
#include <hip/hip_runtime.h>
#include <hip/hip_bf16.h>
#include <cstddef>

#define B_ 32
#define S_ 2048
#define H_ 1024

typedef short short8 __attribute__((ext_vector_type(8)));
typedef float floatx4 __attribute__((ext_vector_type(4)));

// packed fp32x2 -> bf16x2 (RNE), 1 VALU instr
__device__ inline unsigned int cvt_pk_bf16(float a, float b) {
    unsigned int r;
    asm("v_cvt_pk_bf16_f32 %0, %1, %2" : "=v"(r) : "v"(a), "v"(b));
    return r;
}

// ---------------- kernel 0: pack W2 = attn_W[:, 1024:2048] to bf16 [1024][1024] ----
__global__ void pack_w2(const float* __restrict__ W, unsigned short* __restrict__ W2) {
    int i = blockIdx.x * 256 + threadIdx.x;      // 262144 threads, 4 elems each
    int n = i >> 8;                              // 256 float4 per row
    int k4 = (i & 255) * 4;
    float4 v = *reinterpret_cast<const float4*>(W + (size_t)n * 2048 + 1024 + k4);
    uint2 o;
    o.x = cvt_pk_bf16(v.x, v.y);
    o.y = cvt_pk_bf16(v.z, v.w);
    *reinterpret_cast<uint2*>(W2 + (size_t)n * 1024 + k4) = o;
}

// ---------------- kernel 1: hid_proj[b][h] = hidden[b,:] . W[h, 0:1024] + bias[h] ---
__global__ void hid_proj_kernel(const float* __restrict__ hidden,
                                const float* __restrict__ W,
                                const float* __restrict__ bias,
                                float* __restrict__ hp) {
    int h = blockIdx.x;
    int t = threadIdx.x;
    __shared__ float red[32][257];
    __shared__ float red2[32][8];
    float psum[32];
#pragma unroll
    for (int b = 0; b < 32; b++) psum[b] = 0.f;
    const float* wrow = W + (size_t)h * 2048;
    for (int c = 0; c < 4; c++) {
        int k = c * 256 + t;
        float w = wrow[k];
#pragma unroll
        for (int b = 0; b < 32; b++) psum[b] += hidden[b * 1024 + k] * w;
    }
#pragma unroll
    for (int b = 0; b < 32; b++) red[b][t] = psum[b];
    __syncthreads();
    {
        int b = t >> 3, j = t & 7;
        float s = 0.f;
#pragma unroll
        for (int q = 0; q < 32; q++) s += red[b][j * 32 + q];
        red2[b][j] = s;
    }
    __syncthreads();
    if (t < 32) {
        float tot = 0.f;
#pragma unroll
        for (int j = 0; j < 8; j++) tot += red2[t][j];
        hp[t * 1024 + h] = tot + bias[h];
    }
}

// ---------------- kernel 2: fused score GEMM -----------------------------------
// scores[b][s] = sum_h tanh(hid_proj[b][h] + sum_k enc[s,b,k]*W2[h,k]) * v[h]
// A = enc viewed as [65536][1024] fp32 (row m = s*32+b), B = W2 bf16 [1024][1024].
// Block: 128 m-rows, loops all 8 n-tiles of 128 so the v-dot completes in-block.
#define BM 128
#define BK 64
#define LDA 72   // padded bf16 row stride (144 B: 16B-aligned, balanced banks)

__global__ __launch_bounds__(256, 2) void score_gemm(
    const float* __restrict__ enc,
    const unsigned short* __restrict__ W2,
    const float* __restrict__ hp,
    const float* __restrict__ vw,
    float* __restrict__ scores) {
    __shared__ alignas(16) unsigned short As[BM * LDA];
    __shared__ alignas(16) unsigned short Bs[BM * LDA];
    __shared__ float scoreAcc[BM][2];

    const int tid = threadIdx.x;
    const int lane = tid & 63;
    const int w = tid >> 6;
    const int wr = w >> 1, wc = w & 1;
    const int lr = lane & 15, lg = lane >> 4;
    const int mt = blockIdx.x;

    const int srow = tid >> 1;   // 0..127
    const int shalf = tid & 1;   // which 32-element half of the 64-wide k-slab
    const float* aBase = enc + (size_t)(mt * BM + srow) * H_ + shalf * 32;

    if (tid < BM) { scoreAcc[tid][0] = 0.f; scoreAcc[tid][1] = 0.f; }

    for (int nt = 0; nt < 8; nt++) {
        floatx4 acc[4][4];
#pragma unroll
        for (int mi = 0; mi < 4; mi++)
#pragma unroll
            for (int ni = 0; ni < 4; ni++) acc[mi][ni] = (floatx4)0.f;

        const unsigned short* bBase = W2 + (size_t)(nt * 128 + srow) * 1024 + shalf * 32;

        for (int kt = 0; kt < 16; kt++) {
            // global loads for this K-slab (issued before barrier: overlaps prev MFMA)
            float4 af[8];
            const float4* ap = reinterpret_cast<const float4*>(aBase + kt * 64);
#pragma unroll
            for (int i = 0; i < 8; i++) af[i] = ap[i];
            short8 bfv[4];
            const short8* bp = reinterpret_cast<const short8*>(bBase + kt * 64);
#pragma unroll
            for (int i = 0; i < 4; i++) bfv[i] = bp[i];

            __syncthreads();   // previous tile fully consumed
#pragma unroll
            for (int i = 0; i < 4; i++) {
                union { short8 s; unsigned int u[4]; } o;
                o.u[0] = cvt_pk_bf16(af[2 * i].x, af[2 * i].y);
                o.u[1] = cvt_pk_bf16(af[2 * i].z, af[2 * i].w);
                o.u[2] = cvt_pk_bf16(af[2 * i + 1].x, af[2 * i + 1].y);
                o.u[3] = cvt_pk_bf16(af[2 * i + 1].z, af[2 * i + 1].w);
                *reinterpret_cast<short8*>(&As[srow * LDA + shalf * 32 + i * 8]) = o.s;
                *reinterpret_cast<short8*>(&Bs[srow * LDA + shalf * 32 + i * 8]) = bfv[i];
            }
            __syncthreads();

#pragma unroll
            for (int kk = 0; kk < 2; kk++) {
                short8 afr[4], bfr[4];
#pragma unroll
                for (int mi = 0; mi < 4; mi++)
                    afr[mi] = *reinterpret_cast<const short8*>(
                        &As[(wr * 64 + mi * 16 + lr) * LDA + kk * 32 + lg * 8]);
#pragma unroll
                for (int ni = 0; ni < 4; ni++)
                    bfr[ni] = *reinterpret_cast<const short8*>(
                        &Bs[(wc * 64 + ni * 16 + lr) * LDA + kk * 32 + lg * 8]);
#pragma unroll
                for (int mi = 0; mi < 4; mi++)
#pragma unroll
                    for (int ni = 0; ni < 4; ni++)
                        acc[mi][ni] = __builtin_amdgcn_mfma_f32_16x16x32_bf16(
                            afr[mi], bfr[ni], acc[mi][ni], 0, 0, 0);
            }
        }

        // epilogue: tanh(e + hid_proj) * v, reduce over the 128 h's of this n-tile
        const int colBase = nt * 128 + wc * 64;
        float vv[4];
#pragma unroll
        for (int ni = 0; ni < 4; ni++) vv[ni] = vw[colBase + ni * 16 + lr];
#pragma unroll
        for (int mi = 0; mi < 4; mi++) {
            const int row = wr * 64 + mi * 16 + lg * 4;
#pragma unroll
            for (int i = 0; i < 4; i++) {
                const int b = (row + i) & 31;
                const float* hprow = hp + b * 1024 + colBase;
                float s = 0.f;
#pragma unroll
                for (int ni = 0; ni < 4; ni++) {
                    float e = acc[mi][ni][i] + hprow[ni * 16 + lr];
                    float e2 = __expf(2.0f * e);
                    float th = 1.0f - 2.0f * __builtin_amdgcn_rcpf(e2 + 1.0f);
                    s += th * vv[ni];
                }
                s += __shfl_xor(s, 1, 16);
                s += __shfl_xor(s, 2, 16);
                s += __shfl_xor(s, 4, 16);
                s += __shfl_xor(s, 8, 16);
                if (lr == 0) scoreAcc[row + i][wc] += s;
            }
        }
    }

    __syncthreads();
    if (tid < BM) {
        int m = mt * BM + tid;
        int s = m >> 5, b = m & 31;
        scores[b * S_ + s] = scoreAcc[tid][0] + scoreAcc[tid][1];
    }
}

// ---------------- kernel 3: softmax over s, per b -------------------------------
__global__ void softmax_kernel(const float* __restrict__ scores, float* __restrict__ out) {
    int b = blockIdx.x, t = threadIdx.x;
    __shared__ float red[16];
    const float* row = scores + b * S_;
    float vals[8];
    float lmax = -1e30f;
#pragma unroll
    for (int i = 0; i < 8; i++) { vals[i] = row[i * 256 + t]; lmax = fmaxf(lmax, vals[i]); }
#pragma unroll
    for (int off = 32; off; off >>= 1) lmax = fmaxf(lmax, __shfl_xor(lmax, off, 64));
    if ((t & 63) == 0) red[t >> 6] = lmax;
    __syncthreads();
    float gmax = fmaxf(fmaxf(red[0], red[1]), fmaxf(red[2], red[3]));
    float lsum = 0.f;
#pragma unroll
    for (int i = 0; i < 8; i++) { vals[i] = __expf(vals[i] - gmax); lsum += vals[i]; }
#pragma unroll
    for (int off = 32; off; off >>= 1) lsum += __shfl_xor(lsum, off, 64);
    if ((t & 63) == 0) red[8 + (t >> 6)] = lsum;
    __syncthreads();
    float inv = 1.0f / (red[8] + red[9] + red[10] + red[11]);
#pragma unroll
    for (int i = 0; i < 8; i++) out[b * S_ + i * 256 + t] = vals[i] * inv;
}

// ---------------- kernel 4: context[b][h] = sum_s w[b][s] * enc[s][b][h] --------
__global__ void context_kernel(const float* __restrict__ enc,
                               const float* __restrict__ wts,
                               float* __restrict__ ctx) {
    int t = threadIdx.x;
    int hc = blockIdx.x & 3;
    int b = (blockIdx.x >> 2) & 31;
    int sc = blockIdx.x >> 7;            // 0..15
    int h = hc * 256 + t;
    const float* w = wts + b * S_ + sc * 128;
    const float* e = enc + (size_t)(sc * 128) * (B_ * H_) + b * H_ + h;
    float acc = 0.f;
#pragma unroll 4
    for (int s = 0; s < 128; s++)
        acc += w[s] * e[(size_t)s * (B_ * H_)];
    atomicAdd(&ctx[b * H_ + h], acc);
}

extern "C" void kernel_launch(void* const* d_in, const int* in_sizes, int n_in,
                              void* d_out, int out_size, void* d_ws, size_t ws_size,
                              hipStream_t stream) {
    const float* hidden = (const float*)d_in[0];
    const float* enc    = (const float*)d_in[1];
    const float* attn_W = (const float*)d_in[2];
    const float* attn_b = (const float*)d_in[3];
    const float* v_W    = (const float*)d_in[4];
    float* out = (float*)d_out;

    char* ws = (char*)d_ws;
    unsigned short* W2bf = (unsigned short*)ws;                       // 2 MB
    float* hp     = (float*)(ws + (2u << 20));                        // 128 KB
    float* scores = (float*)(ws + (2u << 20) + (128u << 10));         // 256 KB

    pack_w2<<<1024, 256, 0, stream>>>(attn_W, W2bf);
    hid_proj_kernel<<<1024, 256, 0, stream>>>(hidden, attn_W, attn_b, hp);
    score_gemm<<<512, 256, 0, stream>>>(enc, W2bf, hp, v_W, scores);
    softmax_kernel<<<32, 256, 0, stream>>>(scores, out + B_ * H_);
    hipMemsetAsync(out, 0, B_ * H_ * sizeof(float), stream);
    context_kernel<<<2048, 256, 0, stream>>>(enc, out + B_ * H_, out);
}

// Round 2
// 706.111 us; speedup vs baseline: 1.1837x; 1.1837x over previous
//
#include <hip/hip_runtime.h>
#include <hip/hip_bf16.h>
#include <cstddef>

#define B_ 32
#define S_ 2048
#define H_ 1024

typedef short short8 __attribute__((ext_vector_type(8)));
typedef float floatx4 __attribute__((ext_vector_type(4)));

// packed fp32x2 -> bf16x2 (RNE), 1 VALU instr
__device__ inline unsigned int cvt_pk_bf16(float a, float b) {
    unsigned int r;
    asm("v_cvt_pk_bf16_f32 %0, %1, %2" : "=v"(r) : "v"(a), "v"(b));
    return r;
}

// ---------------- kernel 0a: enc fp32 -> bf16 [65536][1024] ---------------------
__global__ void conv_enc(const float* __restrict__ enc, unsigned short* __restrict__ encb) {
    size_t i = (size_t)blockIdx.x * 256 + threadIdx.x;   // 8.39M threads, 8 elems each
    const float4* p = reinterpret_cast<const float4*>(enc) + i * 2;
    float4 v0 = p[0], v1 = p[1];
    union { short8 s; unsigned int u[4]; } o;
    o.u[0] = cvt_pk_bf16(v0.x, v0.y);
    o.u[1] = cvt_pk_bf16(v0.z, v0.w);
    o.u[2] = cvt_pk_bf16(v1.x, v1.y);
    o.u[3] = cvt_pk_bf16(v1.z, v1.w);
    reinterpret_cast<short8*>(encb)[i] = o.s;
}

// ---------------- kernel 0b: pack W2 = attn_W[:, 1024:2048] to bf16 -------------
__global__ void pack_w2(const float* __restrict__ W, unsigned short* __restrict__ W2) {
    int i = blockIdx.x * 256 + threadIdx.x;
    int n = i >> 8;
    int k4 = (i & 255) * 4;
    float4 v = *reinterpret_cast<const float4*>(W + (size_t)n * 2048 + 1024 + k4);
    uint2 o;
    o.x = cvt_pk_bf16(v.x, v.y);
    o.y = cvt_pk_bf16(v.z, v.w);
    *reinterpret_cast<uint2*>(W2 + (size_t)n * 1024 + k4) = o;
}

// ---------------- kernel 1: hid_proj[b][h] = hidden[b,:] . W[h, 0:1024] + bias ---
__global__ void hid_proj_kernel(const float* __restrict__ hidden,
                                const float* __restrict__ W,
                                const float* __restrict__ bias,
                                float* __restrict__ hp) {
    int h = blockIdx.x;
    int t = threadIdx.x;
    __shared__ float red[32][257];
    __shared__ float red2[32][8];
    float psum[32];
#pragma unroll
    for (int b = 0; b < 32; b++) psum[b] = 0.f;
    const float* wrow = W + (size_t)h * 2048;
    for (int c = 0; c < 4; c++) {
        int k = c * 256 + t;
        float w = wrow[k];
#pragma unroll
        for (int b = 0; b < 32; b++) psum[b] += hidden[b * 1024 + k] * w;
    }
#pragma unroll
    for (int b = 0; b < 32; b++) red[b][t] = psum[b];
    __syncthreads();
    {
        int b = t >> 3, j = t & 7;
        float s = 0.f;
#pragma unroll
        for (int q = 0; q < 32; q++) s += red[b][j * 32 + q];
        red2[b][j] = s;
    }
    __syncthreads();
    if (t < 32) {
        float tot = 0.f;
#pragma unroll
        for (int j = 0; j < 8; j++) tot += red2[t][j];
        hp[t * 1024 + h] = tot + bias[h];
    }
}

// ---------------- kernel 2: fused score GEMM -----------------------------------
// scores[b][s] = sum_h tanh(hid_proj[b][h] + sum_k enc[s,b,k]*W2[h,k]) * v[h]
// A = enc [65536][1024] (row m = s*32+b), B = W2 bf16 [1024][1024] (rows = h).
// Block: 128 m-rows; 4 n-passes of 256 cols; register-prefetch pipelined K-loop;
// XOR-8 LDS swizzle (stride 64 shorts) -> conflict-free b128 LDS traffic.
template<bool BF16A>
__global__ __launch_bounds__(256, 2) void score_gemm(
    const void* __restrict__ Ap,
    const unsigned short* __restrict__ W2,
    const float* __restrict__ hp,
    const float* __restrict__ vw,
    float* __restrict__ scores)
{
    __shared__ alignas(16) unsigned short As[128 * 64];
    __shared__ alignas(16) unsigned short Bs[256 * 64];
    __shared__ float scoreAcc[128][2];

    const int tid = threadIdx.x;
    const int lane = tid & 63;
    const int w = tid >> 6, wr = w >> 1, wc = w & 1;
    const int lr = lane & 15, lg = lane >> 4;
    const int mt = blockIdx.x;
    const int arow = tid >> 1, ahalf = tid & 1;
    const int lx = lr & 7;          // read-side xor key (row & 7)
    const int axk = arow & 7;       // A write xor key
    const int bxk = tid & 7;        // B write xor key

    const float* aF = (const float*)Ap + (size_t)(mt * 128 + arow) * H_ + ahalf * 32;
    const unsigned short* aB = (const unsigned short*)Ap + (size_t)(mt * 128 + arow) * H_ + ahalf * 32;

    if (tid < 128) { scoreAcc[tid][0] = 0.f; scoreAcc[tid][1] = 0.f; }

    short8 a8[4]; float4 af[8]; short8 b8[8];

    // prefetch (nt=0, kt=0)
    if (BF16A) {
        const short8* ap = reinterpret_cast<const short8*>(aB);
#pragma unroll
        for (int i = 0; i < 4; i++) a8[i] = ap[i];
    } else {
        const float4* ap = reinterpret_cast<const float4*>(aF);
#pragma unroll
        for (int i = 0; i < 8; i++) af[i] = ap[i];
    }
    {
        const short8* bp = reinterpret_cast<const short8*>(W2 + (size_t)tid * H_);
#pragma unroll
        for (int j = 0; j < 8; j++) b8[j] = bp[j];
    }

    for (int nt = 0; nt < 4; nt++) {
        floatx4 acc[4][8];
#pragma unroll
        for (int mi = 0; mi < 4; mi++)
#pragma unroll
            for (int ni = 0; ni < 8; ni++) acc[mi][ni] = (floatx4)0.f;

        for (int kt = 0; kt < 16; kt++) {
            __syncthreads();                       // prev tile fully consumed
            if (BF16A) {
#pragma unroll
                for (int i = 0; i < 4; i++)
                    *reinterpret_cast<short8*>(&As[arow * 64 + ((ahalf * 4 + i) ^ axk) * 8]) = a8[i];
            } else {
#pragma unroll
                for (int i = 0; i < 4; i++) {
                    union { short8 s; unsigned int u[4]; } o;
                    o.u[0] = cvt_pk_bf16(af[2 * i].x, af[2 * i].y);
                    o.u[1] = cvt_pk_bf16(af[2 * i].z, af[2 * i].w);
                    o.u[2] = cvt_pk_bf16(af[2 * i + 1].x, af[2 * i + 1].y);
                    o.u[3] = cvt_pk_bf16(af[2 * i + 1].z, af[2 * i + 1].w);
                    *reinterpret_cast<short8*>(&As[arow * 64 + ((ahalf * 4 + i) ^ axk) * 8]) = o.s;
                }
            }
#pragma unroll
            for (int j = 0; j < 8; j++)
                *reinterpret_cast<short8*>(&Bs[tid * 64 + ((j ^ bxk) * 8)]) = b8[j];
            __syncthreads();

            // prefetch next K-slab (or next nt's first slab) — hides latency
            // behind the MFMA section / epilogue below
            const int pnt = (kt < 15) ? nt : nt + 1;
            const int pkt = (kt < 15) ? kt + 1 : 0;
            if (pnt < 4) {
                if (BF16A) {
                    const short8* ap = reinterpret_cast<const short8*>(aB + pkt * 64);
#pragma unroll
                    for (int i = 0; i < 4; i++) a8[i] = ap[i];
                } else {
                    const float4* ap = reinterpret_cast<const float4*>(aF + pkt * 64);
#pragma unroll
                    for (int i = 0; i < 8; i++) af[i] = ap[i];
                }
                const short8* bp = reinterpret_cast<const short8*>(W2 + (size_t)(pnt * 256 + tid) * H_ + pkt * 64);
#pragma unroll
                for (int j = 0; j < 8; j++) b8[j] = bp[j];
            }

#pragma unroll
            for (int kk = 0; kk < 2; kk++) {
                const int g = (kk * 4 + lg) ^ lx;
                short8 afr[4], bfr[8];
#pragma unroll
                for (int mi = 0; mi < 4; mi++)
                    afr[mi] = *reinterpret_cast<const short8*>(&As[(wr * 64 + mi * 16 + lr) * 64 + g * 8]);
#pragma unroll
                for (int ni = 0; ni < 8; ni++)
                    bfr[ni] = *reinterpret_cast<const short8*>(&Bs[(wc * 128 + ni * 16 + lr) * 64 + g * 8]);
#pragma unroll
                for (int mi = 0; mi < 4; mi++)
#pragma unroll
                    for (int ni = 0; ni < 8; ni++)
                        acc[mi][ni] = __builtin_amdgcn_mfma_f32_16x16x32_bf16(
                            afr[mi], bfr[ni], acc[mi][ni], 0, 0, 0);
            }
        }

        // epilogue: tanh(e + hid_proj) * v, reduce over this pass's 256 h's
        const int colBase = nt * 256 + wc * 128;
        float vv[8];
#pragma unroll
        for (int ni = 0; ni < 8; ni++) vv[ni] = vw[colBase + ni * 16 + lr];
#pragma unroll
        for (int mi = 0; mi < 4; mi++) {
            const int row = wr * 64 + mi * 16 + lg * 4;
#pragma unroll
            for (int i = 0; i < 4; i++) {
                const int b = (row + i) & 31;
                const float* hprow = hp + b * H_ + colBase;
                float s = 0.f;
#pragma unroll
                for (int ni = 0; ni < 8; ni++) {
                    float e = acc[mi][ni][i] + hprow[ni * 16 + lr];
                    float e2 = __expf(2.0f * e);
                    float th = 1.0f - 2.0f * __builtin_amdgcn_rcpf(e2 + 1.0f);
                    s += th * vv[ni];
                }
                s += __shfl_xor(s, 1, 16);
                s += __shfl_xor(s, 2, 16);
                s += __shfl_xor(s, 4, 16);
                s += __shfl_xor(s, 8, 16);
                if (lr == 0) scoreAcc[row + i][wc] += s;
            }
        }
    }

    __syncthreads();
    if (tid < 128) {
        int m = mt * 128 + tid;
        scores[(m & 31) * S_ + (m >> 5)] = scoreAcc[tid][0] + scoreAcc[tid][1];
    }
}

// ---------------- kernel 3: softmax over s, per b -------------------------------
__global__ void softmax_kernel(const float* __restrict__ scores, float* __restrict__ out) {
    int b = blockIdx.x, t = threadIdx.x;
    __shared__ float red[16];
    const float* row = scores + b * S_;
    float vals[8];
    float lmax = -1e30f;
#pragma unroll
    for (int i = 0; i < 8; i++) { vals[i] = row[i * 256 + t]; lmax = fmaxf(lmax, vals[i]); }
#pragma unroll
    for (int off = 32; off; off >>= 1) lmax = fmaxf(lmax, __shfl_xor(lmax, off, 64));
    if ((t & 63) == 0) red[t >> 6] = lmax;
    __syncthreads();
    float gmax = fmaxf(fmaxf(red[0], red[1]), fmaxf(red[2], red[3]));
    float lsum = 0.f;
#pragma unroll
    for (int i = 0; i < 8; i++) { vals[i] = __expf(vals[i] - gmax); lsum += vals[i]; }
#pragma unroll
    for (int off = 32; off; off >>= 1) lsum += __shfl_xor(lsum, off, 64);
    if ((t & 63) == 0) red[8 + (t >> 6)] = lsum;
    __syncthreads();
    float inv = 1.0f / (red[8] + red[9] + red[10] + red[11]);
#pragma unroll
    for (int i = 0; i < 8; i++) out[b * S_ + i * 256 + t] = vals[i] * inv;
}

// ---------------- kernel 4: context[b][h] = sum_s w[b][s] * enc[s][b][h] --------
__global__ void context_kernel(const float* __restrict__ enc,
                               const float* __restrict__ wts,
                               float* __restrict__ ctx) {
    int t = threadIdx.x;
    int hc = blockIdx.x & 3;
    int b = (blockIdx.x >> 2) & 31;
    int sc = blockIdx.x >> 7;            // 0..15
    int h = hc * 256 + t;
    const float* w = wts + b * S_ + sc * 128;
    const float* e = enc + (size_t)(sc * 128) * (B_ * H_) + b * H_ + h;
    float acc = 0.f;
#pragma unroll 4
    for (int s = 0; s < 128; s++)
        acc += w[s] * e[(size_t)s * (B_ * H_)];
    atomicAdd(&ctx[b * H_ + h], acc);
}

extern "C" void kernel_launch(void* const* d_in, const int* in_sizes, int n_in,
                              void* d_out, int out_size, void* d_ws, size_t ws_size,
                              hipStream_t stream) {
    const float* hidden = (const float*)d_in[0];
    const float* enc    = (const float*)d_in[1];
    const float* attn_W = (const float*)d_in[2];
    const float* attn_b = (const float*)d_in[3];
    const float* v_W    = (const float*)d_in[4];
    float* out = (float*)d_out;

    char* ws = (char*)d_ws;
    const size_t ENCB_BYTES = (size_t)S_ * B_ * H_ * 2;   // 128 MiB
    const size_t W2_BYTES   = (size_t)H_ * H_ * 2;        // 2 MiB
    const bool big = ws_size >= ENCB_BYTES + W2_BYTES + (1u << 20);

    unsigned short* encb = nullptr;
    unsigned short* W2bf;
    float* hp;
    float* scores;
    if (big) {
        encb   = (unsigned short*)ws;
        W2bf   = (unsigned short*)(ws + ENCB_BYTES);
        hp     = (float*)(ws + ENCB_BYTES + W2_BYTES);
        scores = (float*)(ws + ENCB_BYTES + W2_BYTES + (256u << 10));
    } else {
        W2bf   = (unsigned short*)ws;
        hp     = (float*)(ws + W2_BYTES);
        scores = (float*)(ws + W2_BYTES + (256u << 10));
    }

    pack_w2<<<1024, 256, 0, stream>>>(attn_W, W2bf);
    hid_proj_kernel<<<1024, 256, 0, stream>>>(hidden, attn_W, attn_b, hp);
    if (big) {
        conv_enc<<<32768, 256, 0, stream>>>(enc, encb);
        score_gemm<true><<<512, 256, 0, stream>>>((const void*)encb, W2bf, hp, v_W, scores);
    } else {
        score_gemm<false><<<512, 256, 0, stream>>>((const void*)enc, W2bf, hp, v_W, scores);
    }
    softmax_kernel<<<32, 256, 0, stream>>>(scores, out + B_ * H_);
    hipMemsetAsync(out, 0, B_ * H_ * sizeof(float), stream);
    context_kernel<<<2048, 256, 0, stream>>>(enc, out + B_ * H_, out);
}

// Round 3
// 699.298 us; speedup vs baseline: 1.1952x; 1.0097x over previous
//
#include <hip/hip_runtime.h>
#include <hip/hip_bf16.h>
#include <cstddef>

#define B_ 32
#define S_ 2048
#define H_ 1024

typedef short short8 __attribute__((ext_vector_type(8)));
typedef float floatx4 __attribute__((ext_vector_type(4)));

// packed fp32x2 -> bf16x2 (RNE), 1 VALU instr
__device__ inline unsigned int cvt_pk_bf16(float a, float b) {
    unsigned int r;
    asm("v_cvt_pk_bf16_f32 %0, %1, %2" : "=v"(r) : "v"(a), "v"(b));
    return r;
}

// ---------------- kernel 0a: enc fp32 -> bf16 [65536][1024] ---------------------
__global__ void conv_enc(const float* __restrict__ enc, unsigned short* __restrict__ encb) {
    size_t i = (size_t)blockIdx.x * 256 + threadIdx.x;   // 8.39M threads, 8 elems each
    const float4* p = reinterpret_cast<const float4*>(enc) + i * 2;
    float4 v0 = p[0], v1 = p[1];
    union { short8 s; unsigned int u[4]; } o;
    o.u[0] = cvt_pk_bf16(v0.x, v0.y);
    o.u[1] = cvt_pk_bf16(v0.z, v0.w);
    o.u[2] = cvt_pk_bf16(v1.x, v1.y);
    o.u[3] = cvt_pk_bf16(v1.z, v1.w);
    reinterpret_cast<short8*>(encb)[i] = o.s;
}

// ---------------- kernel 0b: pack W2 = attn_W[:, 1024:2048] to bf16 -------------
__global__ void pack_w2(const float* __restrict__ W, unsigned short* __restrict__ W2) {
    int i = blockIdx.x * 256 + threadIdx.x;
    int n = i >> 8;
    int k4 = (i & 255) * 4;
    float4 v = *reinterpret_cast<const float4*>(W + (size_t)n * 2048 + 1024 + k4);
    uint2 o;
    o.x = cvt_pk_bf16(v.x, v.y);
    o.y = cvt_pk_bf16(v.z, v.w);
    *reinterpret_cast<uint2*>(W2 + (size_t)n * 1024 + k4) = o;
}

// ---------------- kernel 1: hid_proj[b][h] = hidden[b,:] . W[h, 0:1024] + bias ---
__global__ void hid_proj_kernel(const float* __restrict__ hidden,
                                const float* __restrict__ W,
                                const float* __restrict__ bias,
                                float* __restrict__ hp) {
    int h = blockIdx.x;
    int t = threadIdx.x;
    __shared__ float red[32][257];
    __shared__ float red2[32][8];
    float psum[32];
#pragma unroll
    for (int b = 0; b < 32; b++) psum[b] = 0.f;
    const float* wrow = W + (size_t)h * 2048;
    for (int c = 0; c < 4; c++) {
        int k = c * 256 + t;
        float w = wrow[k];
#pragma unroll
        for (int b = 0; b < 32; b++) psum[b] += hidden[b * 1024 + k] * w;
    }
#pragma unroll
    for (int b = 0; b < 32; b++) red[b][t] = psum[b];
    __syncthreads();
    {
        int b = t >> 3, j = t & 7;
        float s = 0.f;
#pragma unroll
        for (int q = 0; q < 32; q++) s += red[b][j * 32 + q];
        red2[b][j] = s;
    }
    __syncthreads();
    if (t < 32) {
        float tot = 0.f;
#pragma unroll
        for (int j = 0; j < 8; j++) tot += red2[t][j];
        hp[t * 1024 + h] = tot + bias[h];
    }
}

// ---------------- kernel 2: fused score GEMM -----------------------------------
// scores[b][s] += sum_{h in ntile} tanh(hp[b][h] + sum_k enc[s,b,k]*W2[h,k]) * v[h]
// Block tile 128m x 128n, grid = 512 mt x 8 nt (nt in low bits for A-tile L3
// sharing). 4 waves of 64x64 -> acc[4][4] (64 AGPR) so 3 waves/SIMD fit ->
// 12 waves/CU. XOR-8 LDS swizzle, register-prefetch pipelined K-loop.
// Partial v-dot atomically accumulated into zeroed scores.
template<bool BF16A>
__global__ __launch_bounds__(256, 3) void score_gemm(
    const void* __restrict__ Ap,
    const unsigned short* __restrict__ W2,
    const float* __restrict__ hp,
    const float* __restrict__ vw,
    float* __restrict__ scores)
{
    __shared__ alignas(16) unsigned short As[128 * 64];
    __shared__ alignas(16) unsigned short Bs[128 * 64];

    const int tid = threadIdx.x;
    const int lane = tid & 63;
    const int w = tid >> 6, wr = w >> 1, wc = w & 1;
    const int lr = lane & 15, lg = lane >> 4;
    const int bid = blockIdx.x;
    const int nt = bid & 7, mt = bid >> 3;
    const int row = tid >> 1, half = tid & 1;   // staging: 2 threads per row
    const int xk = row & 7;                     // write-side xor key
    const int lx = lr & 7;                      // read-side xor key

    const float* aF = (const float*)Ap + (size_t)(mt * 128 + row) * H_ + half * 32;
    const unsigned short* aB = (const unsigned short*)Ap + (size_t)(mt * 128 + row) * H_ + half * 32;
    const unsigned short* bP = W2 + (size_t)(nt * 128 + row) * H_ + half * 32;

    short8 a8[4], b8[4]; float4 af[8];

    // prefetch kt=0
    if (BF16A) {
        const short8* p = reinterpret_cast<const short8*>(aB);
#pragma unroll
        for (int i = 0; i < 4; i++) a8[i] = p[i];
    } else {
        const float4* p = reinterpret_cast<const float4*>(aF);
#pragma unroll
        for (int i = 0; i < 8; i++) af[i] = p[i];
    }
    {
        const short8* p = reinterpret_cast<const short8*>(bP);
#pragma unroll
        for (int i = 0; i < 4; i++) b8[i] = p[i];
    }

    floatx4 acc[4][4];
#pragma unroll
    for (int mi = 0; mi < 4; mi++)
#pragma unroll
        for (int ni = 0; ni < 4; ni++) acc[mi][ni] = (floatx4)0.f;

    for (int kt = 0; kt < 16; kt++) {
        __syncthreads();                  // prev tile fully consumed
        if (BF16A) {
#pragma unroll
            for (int i = 0; i < 4; i++)
                *reinterpret_cast<short8*>(&As[row * 64 + ((half * 4 + i) ^ xk) * 8]) = a8[i];
        } else {
#pragma unroll
            for (int i = 0; i < 4; i++) {
                union { short8 s; unsigned int u[4]; } o;
                o.u[0] = cvt_pk_bf16(af[2 * i].x, af[2 * i].y);
                o.u[1] = cvt_pk_bf16(af[2 * i].z, af[2 * i].w);
                o.u[2] = cvt_pk_bf16(af[2 * i + 1].x, af[2 * i + 1].y);
                o.u[3] = cvt_pk_bf16(af[2 * i + 1].z, af[2 * i + 1].w);
                *reinterpret_cast<short8*>(&As[row * 64 + ((half * 4 + i) ^ xk) * 8]) = o.s;
            }
        }
#pragma unroll
        for (int i = 0; i < 4; i++)
            *reinterpret_cast<short8*>(&Bs[row * 64 + ((half * 4 + i) ^ xk) * 8]) = b8[i];
        __syncthreads();

        // prefetch next K-slab — latency hidden behind the MFMA section
        if (kt < 15) {
            if (BF16A) {
                const short8* p = reinterpret_cast<const short8*>(aB + (kt + 1) * 64);
#pragma unroll
                for (int i = 0; i < 4; i++) a8[i] = p[i];
            } else {
                const float4* p = reinterpret_cast<const float4*>(aF + (kt + 1) * 64);
#pragma unroll
                for (int i = 0; i < 8; i++) af[i] = p[i];
            }
            const short8* p = reinterpret_cast<const short8*>(bP + (kt + 1) * 64);
#pragma unroll
            for (int i = 0; i < 4; i++) b8[i] = p[i];
        }

#pragma unroll
        for (int kk = 0; kk < 2; kk++) {
            const int g = (kk * 4 + lg) ^ lx;
            short8 afr[4], bfr[4];
#pragma unroll
            for (int mi = 0; mi < 4; mi++)
                afr[mi] = *reinterpret_cast<const short8*>(&As[(wr * 64 + mi * 16 + lr) * 64 + g * 8]);
#pragma unroll
            for (int ni = 0; ni < 4; ni++)
                bfr[ni] = *reinterpret_cast<const short8*>(&Bs[(wc * 64 + ni * 16 + lr) * 64 + g * 8]);
#pragma unroll
            for (int mi = 0; mi < 4; mi++)
#pragma unroll
                for (int ni = 0; ni < 4; ni++)
                    acc[mi][ni] = __builtin_amdgcn_mfma_f32_16x16x32_bf16(
                        afr[mi], bfr[ni], acc[mi][ni], 0, 0, 0);
        }
    }

    // epilogue: tanh(e + hid_proj) * v, reduce over this block's 128 h's
    const int colBase = nt * 128 + wc * 64;
    float vv[4];
#pragma unroll
    for (int ni = 0; ni < 4; ni++) vv[ni] = vw[colBase + ni * 16 + lr];
#pragma unroll
    for (int mi = 0; mi < 4; mi++) {
        const int rowm = wr * 64 + mi * 16 + lg * 4;
#pragma unroll
        for (int i = 0; i < 4; i++) {
            const int m = mt * 128 + rowm + i;
            const int b = m & 31, sidx = m >> 5;
            const float* hprow = hp + b * H_ + colBase;
            float s = 0.f;
#pragma unroll
            for (int ni = 0; ni < 4; ni++) {
                float e = acc[mi][ni][i] + hprow[ni * 16 + lr];
                float e2 = __expf(2.0f * e);
                float th = 1.0f - 2.0f * __builtin_amdgcn_rcpf(e2 + 1.0f);
                s += th * vv[ni];
            }
            s += __shfl_xor(s, 1, 16);
            s += __shfl_xor(s, 2, 16);
            s += __shfl_xor(s, 4, 16);
            s += __shfl_xor(s, 8, 16);
            if (lr == 0) atomicAdd(&scores[b * S_ + sidx], s);
        }
    }
}

// ---------------- kernel 3: softmax over s, per b -------------------------------
__global__ void softmax_kernel(const float* __restrict__ scores, float* __restrict__ out) {
    int b = blockIdx.x, t = threadIdx.x;
    __shared__ float red[16];
    const float* row = scores + b * S_;
    float vals[8];
    float lmax = -1e30f;
#pragma unroll
    for (int i = 0; i < 8; i++) { vals[i] = row[i * 256 + t]; lmax = fmaxf(lmax, vals[i]); }
#pragma unroll
    for (int off = 32; off; off >>= 1) lmax = fmaxf(lmax, __shfl_xor(lmax, off, 64));
    if ((t & 63) == 0) red[t >> 6] = lmax;
    __syncthreads();
    float gmax = fmaxf(fmaxf(red[0], red[1]), fmaxf(red[2], red[3]));
    float lsum = 0.f;
#pragma unroll
    for (int i = 0; i < 8; i++) { vals[i] = __expf(vals[i] - gmax); lsum += vals[i]; }
#pragma unroll
    for (int off = 32; off; off >>= 1) lsum += __shfl_xor(lsum, off, 64);
    if ((t & 63) == 0) red[8 + (t >> 6)] = lsum;
    __syncthreads();
    float inv = 1.0f / (red[8] + red[9] + red[10] + red[11]);
#pragma unroll
    for (int i = 0; i < 8; i++) out[b * S_ + i * 256 + t] = vals[i] * inv;
}

// ---------------- kernel 4: context[b][h] = sum_s w[b][s] * enc[s][b][h] --------
// Reads bf16 encb when available (halves HBM traffic), else fp32 enc.
template<bool BF16E>
__global__ void context_kernel(const void* __restrict__ encp,
                               const float* __restrict__ wts,
                               float* __restrict__ ctx) {
    int t = threadIdx.x;
    int hc = blockIdx.x & 1;
    int b = (blockIdx.x >> 1) & 31;
    int sc = blockIdx.x >> 6;            // 0..15
    int h = hc * 512 + t * 2;
    const float* w = wts + b * S_ + sc * 128;
    float acc0 = 0.f, acc1 = 0.f;
    if (BF16E) {
        const unsigned short* e = (const unsigned short*)encp
            + (size_t)(sc * 128) * (B_ * H_) + b * H_ + h;
#pragma unroll 8
        for (int s = 0; s < 128; s++) {
            unsigned int u = *reinterpret_cast<const unsigned int*>(e + (size_t)s * (B_ * H_));
            float ws_ = w[s];
            acc0 += ws_ * __uint_as_float(u << 16);
            acc1 += ws_ * __uint_as_float(u & 0xffff0000u);
        }
    } else {
        const float* e = (const float*)encp + (size_t)(sc * 128) * (B_ * H_) + b * H_ + h;
#pragma unroll 8
        for (int s = 0; s < 128; s++) {
            float ws_ = w[s];
            acc0 += ws_ * e[(size_t)s * (B_ * H_)];
            acc1 += ws_ * e[(size_t)s * (B_ * H_) + 1];
        }
    }
    atomicAdd(&ctx[b * H_ + h], acc0);
    atomicAdd(&ctx[b * H_ + h + 1], acc1);
}

extern "C" void kernel_launch(void* const* d_in, const int* in_sizes, int n_in,
                              void* d_out, int out_size, void* d_ws, size_t ws_size,
                              hipStream_t stream) {
    const float* hidden = (const float*)d_in[0];
    const float* enc    = (const float*)d_in[1];
    const float* attn_W = (const float*)d_in[2];
    const float* attn_b = (const float*)d_in[3];
    const float* v_W    = (const float*)d_in[4];
    float* out = (float*)d_out;

    char* ws = (char*)d_ws;
    const size_t ENCB_BYTES = (size_t)S_ * B_ * H_ * 2;   // 128 MiB
    const size_t W2_BYTES   = (size_t)H_ * H_ * 2;        // 2 MiB
    const bool big = ws_size >= ENCB_BYTES + W2_BYTES + (1u << 20);

    unsigned short* encb = nullptr;
    unsigned short* W2bf;
    float* hp;
    float* scores;
    if (big) {
        encb   = (unsigned short*)ws;
        W2bf   = (unsigned short*)(ws + ENCB_BYTES);
        hp     = (float*)(ws + ENCB_BYTES + W2_BYTES);
        scores = (float*)(ws + ENCB_BYTES + W2_BYTES + (256u << 10));
    } else {
        W2bf   = (unsigned short*)ws;
        hp     = (float*)(ws + W2_BYTES);
        scores = (float*)(ws + W2_BYTES + (256u << 10));
    }

    pack_w2<<<1024, 256, 0, stream>>>(attn_W, W2bf);
    hid_proj_kernel<<<1024, 256, 0, stream>>>(hidden, attn_W, attn_b, hp);
    hipMemsetAsync(scores, 0, B_ * S_ * sizeof(float), stream);
    if (big) {
        conv_enc<<<32768, 256, 0, stream>>>(enc, encb);
        score_gemm<true><<<4096, 256, 0, stream>>>((const void*)encb, W2bf, hp, v_W, scores);
    } else {
        score_gemm<false><<<4096, 256, 0, stream>>>((const void*)enc, W2bf, hp, v_W, scores);
    }
    softmax_kernel<<<32, 256, 0, stream>>>(scores, out + B_ * H_);
    hipMemsetAsync(out, 0, B_ * H_ * sizeof(float), stream);
    if (big) {
        context_kernel<true><<<1024, 256, 0, stream>>>((const void*)encb, out + B_ * H_, out);
    } else {
        context_kernel<false><<<1024, 256, 0, stream>>>((const void*)enc, out + B_ * H_, out);
    }
}

// Round 4
// 641.566 us; speedup vs baseline: 1.3028x; 1.0900x over previous
//
#include <hip/hip_runtime.h>
#include <hip/hip_bf16.h>
#include <cstddef>

#define B_ 32
#define S_ 2048
#define H_ 1024

typedef short short8 __attribute__((ext_vector_type(8)));
typedef float floatx4 __attribute__((ext_vector_type(4)));

// packed fp32x2 -> bf16x2 (RNE), 1 VALU instr
__device__ inline unsigned int cvt_pk_bf16(float a, float b) {
    unsigned int r;
    asm("v_cvt_pk_bf16_f32 %0, %1, %2" : "=v"(r) : "v"(a), "v"(b));
    return r;
}

// async global->LDS DMA, 16B per lane; LDS dest = wave-uniform base + lane*16
__device__ inline void gload_lds16(const unsigned short* g, unsigned short* l) {
    __builtin_amdgcn_global_load_lds(
        (const __attribute__((address_space(1))) unsigned int*)g,
        (__attribute__((address_space(3))) unsigned int*)l, 16, 0, 0);
}

// ---------------- prep: enc -> tiled+swizzled bf16, W2 -> fragment-tiled bf16 ---
// encT: per (mt=m>>7, kt=k>>6) a 16KB tile: shorts[r*64 + ((j7&7)^(r&7))*8 + k&7]
// Bp:   per (nb=n>>4, kt2=k>>5) a 1KB tile, lane-linear: shorts[(lg*16+lr)*8 + k&7]
__global__ void prep_kernel(const float* __restrict__ enc, unsigned short* __restrict__ encT,
                            const float* __restrict__ W, unsigned short* __restrict__ Bp) {
    int bid = blockIdx.x, t = threadIdx.x;
    if (bid < 32768) {
        int gtid = bid * 256 + t;            // = m*128 + j7
        int m = gtid >> 7, j7 = gtid & 127;
        const float4* p = reinterpret_cast<const float4*>(enc + (size_t)m * H_ + j7 * 8);
        float4 v0 = p[0], v1 = p[1];
        union { short8 s; unsigned int u[4]; } o;
        o.u[0] = cvt_pk_bf16(v0.x, v0.y);
        o.u[1] = cvt_pk_bf16(v0.z, v0.w);
        o.u[2] = cvt_pk_bf16(v1.x, v1.y);
        o.u[3] = cvt_pk_bf16(v1.z, v1.w);
        int tile = (m >> 7) * 16 + (j7 >> 3);
        int r = m & 127;
        int j = (j7 & 7) ^ (r & 7);
        reinterpret_cast<short8*>(encT)[(size_t)tile * 1024 + r * 8 + j] = o.s;
    } else {
        int gtid = (bid - 32768) * 256 + t;  // = n*128 + j7, n<1024
        int n = gtid >> 7, j7 = gtid & 127;
        const float4* p = reinterpret_cast<const float4*>(W + (size_t)n * 2048 + 1024 + j7 * 8);
        float4 v0 = p[0], v1 = p[1];
        union { short8 s; unsigned int u[4]; } o;
        o.u[0] = cvt_pk_bf16(v0.x, v0.y);
        o.u[1] = cvt_pk_bf16(v0.z, v0.w);
        o.u[2] = cvt_pk_bf16(v1.x, v1.y);
        o.u[3] = cvt_pk_bf16(v1.z, v1.w);
        int nb = n >> 4, lr = n & 15, kt2 = j7 >> 2, lg = j7 & 3;
        reinterpret_cast<short8*>(Bp)[(nb * 32 + kt2) * 64 + lg * 16 + lr] = o.s;
    }
}

// ---------------- kernel 1: hid_proj[b][h] = hidden[b,:] . W[h, 0:1024] + bias ---
__global__ void hid_proj_kernel(const float* __restrict__ hidden,
                                const float* __restrict__ W,
                                const float* __restrict__ bias,
                                float* __restrict__ hp) {
    int h = blockIdx.x;
    int t = threadIdx.x;
    __shared__ float red[32][257];
    __shared__ float red2[32][8];
    float psum[32];
#pragma unroll
    for (int b = 0; b < 32; b++) psum[b] = 0.f;
    const float* wrow = W + (size_t)h * 2048;
    for (int c = 0; c < 4; c++) {
        int k = c * 256 + t;
        float w = wrow[k];
#pragma unroll
        for (int b = 0; b < 32; b++) psum[b] += hidden[b * 1024 + k] * w;
    }
#pragma unroll
    for (int b = 0; b < 32; b++) red[b][t] = psum[b];
    __syncthreads();
    {
        int b = t >> 3, j = t & 7;
        float s = 0.f;
#pragma unroll
        for (int q = 0; q < 32; q++) s += red[b][j * 32 + q];
        red2[b][j] = s;
    }
    __syncthreads();
    if (t < 32) {
        float tot = 0.f;
#pragma unroll
        for (int j = 0; j < 8; j++) tot += red2[t][j];
        hp[t * 1024 + h] = tot + bias[h];
    }
}

// ---------------- kernel 2: fused score GEMM (DMA A, direct-frag B) -------------
// Block 128m x 128n; grid 4096 XCD-swizzled so nt-siblings share per-XCD L2.
// A staged by global_load_lds into double-buffered LDS (pre-swizzled tiles);
// B fragments loaded straight from L2 (lane-linear packed), reg double-buffered.
// One barrier per kt.
__global__ __launch_bounds__(256, 3) void score_gemm_t(
    const unsigned short* __restrict__ encT,
    const unsigned short* __restrict__ Bp,
    const float* __restrict__ hp,
    const float* __restrict__ vw,
    float* __restrict__ scores)
{
    __shared__ alignas(16) unsigned short As[2][8192];

    const int tid = threadIdx.x;
    const int lane = tid & 63;
    const int w = tid >> 6, wr = w >> 1, wc = w & 1;
    const int lr = lane & 15, lg = lane >> 4;
    const int lx = lr & 7;

    const int bid = blockIdx.x;
    const int x = bid & 7, j = bid >> 3;
    const int nt = j & 7;
    const int mt = (j >> 3) * 8 + x;      // nt-siblings of mt land on XCD x

    const unsigned short* aT = encT + (size_t)mt * 16 * 8192;
    const short8* bp8 = reinterpret_cast<const short8*>(Bp);

    short8 bpf[2][8];
    // prologue: DMA A(kt=0) -> As[0]; load B(kt=0) frags
    {
        const unsigned short* src = aT + (w * 4) * 512 + lane * 8;
        unsigned short* dst = &As[0][(w * 4) * 512];
#pragma unroll
        for (int i = 0; i < 4; i++) gload_lds16(src + i * 512, dst + i * 512);
#pragma unroll
        for (int kk = 0; kk < 2; kk++)
#pragma unroll
            for (int ni = 0; ni < 4; ni++) {
                int nb = nt * 8 + wc * 4 + ni;
                bpf[0][kk * 4 + ni] = bp8[(nb * 32 + kk) * 64 + lane];
            }
    }

    floatx4 acc[4][4];
#pragma unroll
    for (int mi = 0; mi < 4; mi++)
#pragma unroll
        for (int ni = 0; ni < 4; ni++) acc[mi][ni] = (floatx4)0.f;

#pragma unroll
    for (int kt = 0; kt < 16; kt++) {
        const int cb = kt & 1;
        __syncthreads();   // DMA into As[cb] complete; prior reads of As[cb^1] done
        if (kt < 15) {
            const unsigned short* src = aT + (kt + 1) * 8192 + (w * 4) * 512 + lane * 8;
            unsigned short* dst = &As[cb ^ 1][(w * 4) * 512];
#pragma unroll
            for (int i = 0; i < 4; i++) gload_lds16(src + i * 512, dst + i * 512);
#pragma unroll
            for (int kk = 0; kk < 2; kk++)
#pragma unroll
                for (int ni = 0; ni < 4; ni++) {
                    int nb = nt * 8 + wc * 4 + ni;
                    bpf[cb ^ 1][kk * 4 + ni] = bp8[(nb * 32 + (kt + 1) * 2 + kk) * 64 + lane];
                }
        }
#pragma unroll
        for (int kk = 0; kk < 2; kk++) {
            short8 afr[4];
#pragma unroll
            for (int mi = 0; mi < 4; mi++)
                afr[mi] = *reinterpret_cast<const short8*>(
                    &As[cb][(wr * 64 + mi * 16 + lr) * 64 + ((kk * 4 + lg) ^ lx) * 8]);
#pragma unroll
            for (int mi = 0; mi < 4; mi++)
#pragma unroll
                for (int ni = 0; ni < 4; ni++)
                    acc[mi][ni] = __builtin_amdgcn_mfma_f32_16x16x32_bf16(
                        afr[mi], bpf[cb][kk * 4 + ni], acc[mi][ni], 0, 0, 0);
        }
    }

    // epilogue: tanh(e + hid_proj) * v, reduce over this block's 128 h's
    const int colBase = nt * 128 + wc * 64;
    float vv[4];
#pragma unroll
    for (int ni = 0; ni < 4; ni++) vv[ni] = vw[colBase + ni * 16 + lr];
#pragma unroll
    for (int mi = 0; mi < 4; mi++) {
        const int rowm = wr * 64 + mi * 16 + lg * 4;
#pragma unroll
        for (int i = 0; i < 4; i++) {
            const int m = mt * 128 + rowm + i;
            const int b = m & 31, sidx = m >> 5;
            const float* hprow = hp + b * H_ + colBase;
            float s = 0.f;
#pragma unroll
            for (int ni = 0; ni < 4; ni++) {
                float e = acc[mi][ni][i] + hprow[ni * 16 + lr];
                float e2 = __expf(2.0f * e);
                float th = 1.0f - 2.0f * __builtin_amdgcn_rcpf(e2 + 1.0f);
                s += th * vv[ni];
            }
            s += __shfl_xor(s, 1, 16);
            s += __shfl_xor(s, 2, 16);
            s += __shfl_xor(s, 4, 16);
            s += __shfl_xor(s, 8, 16);
            if (lr == 0) atomicAdd(&scores[b * S_ + sidx], s);
        }
    }
}

// ---------------- kernel 3: softmax over s, per b -------------------------------
__global__ void softmax_kernel(const float* __restrict__ scores, float* __restrict__ out) {
    int b = blockIdx.x, t = threadIdx.x;
    __shared__ float red[16];
    const float* row = scores + b * S_;
    float vals[8];
    float lmax = -1e30f;
#pragma unroll
    for (int i = 0; i < 8; i++) { vals[i] = row[i * 256 + t]; lmax = fmaxf(lmax, vals[i]); }
#pragma unroll
    for (int off = 32; off; off >>= 1) lmax = fmaxf(lmax, __shfl_xor(lmax, off, 64));
    if ((t & 63) == 0) red[t >> 6] = lmax;
    __syncthreads();
    float gmax = fmaxf(fmaxf(red[0], red[1]), fmaxf(red[2], red[3]));
    float lsum = 0.f;
#pragma unroll
    for (int i = 0; i < 8; i++) { vals[i] = __expf(vals[i] - gmax); lsum += vals[i]; }
#pragma unroll
    for (int off = 32; off; off >>= 1) lsum += __shfl_xor(lsum, off, 64);
    if ((t & 63) == 0) red[8 + (t >> 6)] = lsum;
    __syncthreads();
    float inv = 1.0f / (red[8] + red[9] + red[10] + red[11]);
#pragma unroll
    for (int i = 0; i < 8; i++) out[b * S_ + i * 256 + t] = vals[i] * inv;
}

// ---------------- kernel 4: context from tiled bf16 encT ------------------------
__global__ void context_tiled(const unsigned short* __restrict__ encT,
                              const float* __restrict__ wts,
                              float* __restrict__ ctx) {
    int t = threadIdx.x;
    int hc = blockIdx.x & 1;
    int b = (blockIdx.x >> 1) & 31;
    int sc = blockIdx.x >> 6;            // 0..15
    int h = hc * 512 + t * 2;
    const float* w = wts + b * S_ + sc * 128;
    const int jconst = ((h >> 3) & 7) ^ (b & 7);
    const int inrow = jconst * 8 + (h & 7);
    const int ktile = h >> 6;
    float acc0 = 0.f, acc1 = 0.f;
#pragma unroll 4
    for (int s = 0; s < 128; s++) {
        int m = (sc * 128 + s) * 32 + b;
        size_t off = ((size_t)(m >> 7) * 16 + ktile) * 8192 + (m & 127) * 64 + inrow;
        unsigned int u = *reinterpret_cast<const unsigned int*>(encT + off);
        float ws_ = w[s];
        acc0 += ws_ * __uint_as_float(u << 16);
        acc1 += ws_ * __uint_as_float(u & 0xffff0000u);
    }
    atomicAdd(&ctx[b * H_ + h], acc0);
    atomicAdd(&ctx[b * H_ + h + 1], acc1);
}

// ================= fallback path (small workspace): round-3 kernels =============
__global__ void pack_w2_rm(const float* __restrict__ W, unsigned short* __restrict__ W2) {
    int i = blockIdx.x * 256 + threadIdx.x;
    int n = i >> 8;
    int k4 = (i & 255) * 4;
    float4 v = *reinterpret_cast<const float4*>(W + (size_t)n * 2048 + 1024 + k4);
    uint2 o;
    o.x = cvt_pk_bf16(v.x, v.y);
    o.y = cvt_pk_bf16(v.z, v.w);
    *reinterpret_cast<uint2*>(W2 + (size_t)n * 1024 + k4) = o;
}

__global__ __launch_bounds__(256, 3) void score_gemm_f32(
    const float* __restrict__ Ap, const unsigned short* __restrict__ W2,
    const float* __restrict__ hp, const float* __restrict__ vw,
    float* __restrict__ scores)
{
    __shared__ alignas(16) unsigned short As[128 * 64];
    __shared__ alignas(16) unsigned short Bs[128 * 64];
    const int tid = threadIdx.x;
    const int lane = tid & 63;
    const int w = tid >> 6, wr = w >> 1, wc = w & 1;
    const int lr = lane & 15, lg = lane >> 4;
    const int bid = blockIdx.x;
    const int nt = bid & 7, mt = bid >> 3;
    const int row = tid >> 1, half = tid & 1;
    const int xk = row & 7;
    const int lx = lr & 7;
    const float* aF = Ap + (size_t)(mt * 128 + row) * H_ + half * 32;
    const unsigned short* bP = W2 + (size_t)(nt * 128 + row) * H_ + half * 32;
    short8 b8[4]; float4 af[8];
    {
        const float4* p = reinterpret_cast<const float4*>(aF);
#pragma unroll
        for (int i = 0; i < 8; i++) af[i] = p[i];
        const short8* q = reinterpret_cast<const short8*>(bP);
#pragma unroll
        for (int i = 0; i < 4; i++) b8[i] = q[i];
    }
    floatx4 acc[4][4];
#pragma unroll
    for (int mi = 0; mi < 4; mi++)
#pragma unroll
        for (int ni = 0; ni < 4; ni++) acc[mi][ni] = (floatx4)0.f;
    for (int kt = 0; kt < 16; kt++) {
        __syncthreads();
#pragma unroll
        for (int i = 0; i < 4; i++) {
            union { short8 s; unsigned int u[4]; } o;
            o.u[0] = cvt_pk_bf16(af[2 * i].x, af[2 * i].y);
            o.u[1] = cvt_pk_bf16(af[2 * i].z, af[2 * i].w);
            o.u[2] = cvt_pk_bf16(af[2 * i + 1].x, af[2 * i + 1].y);
            o.u[3] = cvt_pk_bf16(af[2 * i + 1].z, af[2 * i + 1].w);
            *reinterpret_cast<short8*>(&As[row * 64 + ((half * 4 + i) ^ xk) * 8]) = o.s;
        }
#pragma unroll
        for (int i = 0; i < 4; i++)
            *reinterpret_cast<short8*>(&Bs[row * 64 + ((half * 4 + i) ^ xk) * 8]) = b8[i];
        __syncthreads();
        if (kt < 15) {
            const float4* p = reinterpret_cast<const float4*>(aF + (kt + 1) * 64);
#pragma unroll
            for (int i = 0; i < 8; i++) af[i] = p[i];
            const short8* q = reinterpret_cast<const short8*>(bP + (kt + 1) * 64);
#pragma unroll
            for (int i = 0; i < 4; i++) b8[i] = q[i];
        }
#pragma unroll
        for (int kk = 0; kk < 2; kk++) {
            const int g = (kk * 4 + lg) ^ lx;
            short8 afr[4], bfr[4];
#pragma unroll
            for (int mi = 0; mi < 4; mi++)
                afr[mi] = *reinterpret_cast<const short8*>(&As[(wr * 64 + mi * 16 + lr) * 64 + g * 8]);
#pragma unroll
            for (int ni = 0; ni < 4; ni++)
                bfr[ni] = *reinterpret_cast<const short8*>(&Bs[(wc * 64 + ni * 16 + lr) * 64 + g * 8]);
#pragma unroll
            for (int mi = 0; mi < 4; mi++)
#pragma unroll
                for (int ni = 0; ni < 4; ni++)
                    acc[mi][ni] = __builtin_amdgcn_mfma_f32_16x16x32_bf16(
                        afr[mi], bfr[ni], acc[mi][ni], 0, 0, 0);
        }
    }
    const int colBase = nt * 128 + wc * 64;
    float vv[4];
#pragma unroll
    for (int ni = 0; ni < 4; ni++) vv[ni] = vw[colBase + ni * 16 + lr];
#pragma unroll
    for (int mi = 0; mi < 4; mi++) {
        const int rowm = wr * 64 + mi * 16 + lg * 4;
#pragma unroll
        for (int i = 0; i < 4; i++) {
            const int m = mt * 128 + rowm + i;
            const int b = m & 31, sidx = m >> 5;
            const float* hprow = hp + b * H_ + colBase;
            float s = 0.f;
#pragma unroll
            for (int ni = 0; ni < 4; ni++) {
                float e = acc[mi][ni][i] + hprow[ni * 16 + lr];
                float e2 = __expf(2.0f * e);
                float th = 1.0f - 2.0f * __builtin_amdgcn_rcpf(e2 + 1.0f);
                s += th * vv[ni];
            }
            s += __shfl_xor(s, 1, 16);
            s += __shfl_xor(s, 2, 16);
            s += __shfl_xor(s, 4, 16);
            s += __shfl_xor(s, 8, 16);
            if (lr == 0) atomicAdd(&scores[b * S_ + sidx], s);
        }
    }
}

__global__ void context_f32(const float* __restrict__ enc,
                            const float* __restrict__ wts,
                            float* __restrict__ ctx) {
    int t = threadIdx.x;
    int hc = blockIdx.x & 1;
    int b = (blockIdx.x >> 1) & 31;
    int sc = blockIdx.x >> 6;
    int h = hc * 512 + t * 2;
    const float* w = wts + b * S_ + sc * 128;
    const float* e = enc + (size_t)(sc * 128) * (B_ * H_) + b * H_ + h;
    float acc0 = 0.f, acc1 = 0.f;
#pragma unroll 8
    for (int s = 0; s < 128; s++) {
        float ws_ = w[s];
        acc0 += ws_ * e[(size_t)s * (B_ * H_)];
        acc1 += ws_ * e[(size_t)s * (B_ * H_) + 1];
    }
    atomicAdd(&ctx[b * H_ + h], acc0);
    atomicAdd(&ctx[b * H_ + h + 1], acc1);
}

extern "C" void kernel_launch(void* const* d_in, const int* in_sizes, int n_in,
                              void* d_out, int out_size, void* d_ws, size_t ws_size,
                              hipStream_t stream) {
    const float* hidden = (const float*)d_in[0];
    const float* enc    = (const float*)d_in[1];
    const float* attn_W = (const float*)d_in[2];
    const float* attn_b = (const float*)d_in[3];
    const float* v_W    = (const float*)d_in[4];
    float* out = (float*)d_out;

    char* ws = (char*)d_ws;
    const size_t ENCT_BYTES = (size_t)S_ * B_ * H_ * 2;   // 128 MiB
    const size_t BP_BYTES   = (size_t)H_ * H_ * 2;        // 2 MiB
    const bool big = ws_size >= ENCT_BYTES + BP_BYTES + (1u << 20);

    if (big) {
        unsigned short* encT = (unsigned short*)ws;
        unsigned short* Bp   = (unsigned short*)(ws + ENCT_BYTES);
        float* hp     = (float*)(ws + ENCT_BYTES + BP_BYTES);
        float* scores = (float*)(ws + ENCT_BYTES + BP_BYTES + (256u << 10));

        prep_kernel<<<33280, 256, 0, stream>>>(enc, encT, attn_W, Bp);
        hid_proj_kernel<<<1024, 256, 0, stream>>>(hidden, attn_W, attn_b, hp);
        hipMemsetAsync(scores, 0, B_ * S_ * sizeof(float), stream);
        score_gemm_t<<<4096, 256, 0, stream>>>(encT, Bp, hp, v_W, scores);
        softmax_kernel<<<32, 256, 0, stream>>>(scores, out + B_ * H_);
        hipMemsetAsync(out, 0, B_ * H_ * sizeof(float), stream);
        context_tiled<<<1024, 256, 0, stream>>>(encT, out + B_ * H_, out);
    } else {
        unsigned short* W2bf = (unsigned short*)ws;
        float* hp     = (float*)(ws + BP_BYTES);
        float* scores = (float*)(ws + BP_BYTES + (256u << 10));

        pack_w2_rm<<<1024, 256, 0, stream>>>(attn_W, W2bf);
        hid_proj_kernel<<<1024, 256, 0, stream>>>(hidden, attn_W, attn_b, hp);
        hipMemsetAsync(scores, 0, B_ * S_ * sizeof(float), stream);
        score_gemm_f32<<<4096, 256, 0, stream>>>(enc, W2bf, hp, v_W, scores);
        softmax_kernel<<<32, 256, 0, stream>>>(scores, out + B_ * H_);
        hipMemsetAsync(out, 0, B_ * H_ * sizeof(float), stream);
        context_f32<<<1024, 256, 0, stream>>>(enc, out + B_ * H_, out);
    }
}